// Round 7
// baseline (708.289 us; speedup 1.0000x reference)
//
#include <hip/hip_runtime.h>
#include <cstdint>

#define BB 128
#define TT 1024
#define NN 256

typedef float f32x4 __attribute__((ext_vector_type(4)));
typedef unsigned long long ull;

// ---------- wave-64 max via value-only DPP fmax chain ----------
#define DPP_F(v, ctrl) __int_as_float(__builtin_amdgcn_update_dpp( \
    __float_as_int(v), __float_as_int(v), ctrl, 0xF, 0xF, false))

__device__ __forceinline__ float wave_max64(float v) {
  v = fmaxf(v, DPP_F(v, 0x111));  // row_shr:1
  v = fmaxf(v, DPP_F(v, 0x112));  // row_shr:2
  v = fmaxf(v, DPP_F(v, 0x114));  // row_shr:4
  v = fmaxf(v, DPP_F(v, 0x118));  // row_shr:8
  v = fmaxf(v, DPP_F(v, 0x142));  // row_bcast:15
  v = fmaxf(v, DPP_F(v, 0x143));  // row_bcast:31
  return __int_as_float(__builtin_amdgcn_readlane(__float_as_int(v), 63));
}

// first-occurrence index of value == M (matches jnp.argmax tie semantics)
__device__ __forceinline__ int first_index_eq(float a0, float a1, float a2,
                                              float a3, float M) {
  unsigned long long e0 = __ballot(a0 == M), e1 = __ballot(a1 == M),
                     e2 = __ballot(a2 == M), e3 = __ballot(a3 == M);
  int best = 1 << 30;
  if (e0) { int c = 4 * (int)__builtin_ctzll(e0);     if (c < best) best = c; }
  if (e1) { int c = 4 * (int)__builtin_ctzll(e1) + 1; if (c < best) best = c; }
  if (e2) { int c = 4 * (int)__builtin_ctzll(e2) + 2; if (c < best) best = c; }
  if (e3) { int c = 4 * (int)__builtin_ctzll(e3) + 3; if (c < best) best = c; }
  return best;
}

// band masks (val >= thr), candidate count, 2nd-smallest candidate != istar
__device__ __forceinline__ void band_scan(float a0, float a1, float a2,
                                          float a3, float thr, int istar,
                                          unsigned long long& m0,
                                          unsigned long long& m1,
                                          unsigned long long& m2,
                                          unsigned long long& m3, int& cnt,
                                          int& i2) {
  m0 = __ballot(a0 >= thr); m1 = __ballot(a1 >= thr);
  m2 = __ballot(a2 >= thr); m3 = __ballot(a3 >= thr);
  cnt = __popcll(m0) + __popcll(m1) + __popcll(m2) + __popcll(m3);
  unsigned long long f0 = m0, f1 = m1, f2 = m2, f3 = m3;
  const unsigned long long qb = 1ull << (istar >> 2);
  const int g = istar & 3;
  if (g == 0) f0 &= ~qb; else if (g == 1) f1 &= ~qb;
  else if (g == 2) f2 &= ~qb; else f3 &= ~qb;
  int best = 1 << 30;
  if (f0) { int c = 4 * (int)__builtin_ctzll(f0);     if (c < best) best = c; }
  if (f1) { int c = 4 * (int)__builtin_ctzll(f1) + 1; if (c < best) best = c; }
  if (f2) { int c = 4 * (int)__builtin_ctzll(f2) + 2; if (c < best) best = c; }
  if (f3) { int c = 4 * (int)__builtin_ctzll(f3) + 3; if (c < best) best = c; }
  i2 = (best == (1 << 30)) ? istar : best;
}

// alpha[idx] via element-select (uniform idx) + readlane
__device__ __forceinline__ float rl_pick(float a0, float a1, float a2, float a3,
                                         int idx) {
  const int g = idx & 3;
  const float v = (g & 2) ? ((g & 1) ? a3 : a2) : ((g & 1) ? a1 : a0);
  return __int_as_float(__builtin_amdgcn_readlane(__float_as_int(v), idx >> 2));
}

// ---------- prep: per (b,t) pot row -> top-2 pot-band(0.21) record ----------
__global__ __launch_bounds__(256) void prep_kernel(
    const float* __restrict__ pot, const int* __restrict__ lens,
    uint32_t* __restrict__ recs) {
  const int wid = threadIdx.x >> 6, lane = threadIdx.x & 63;
  const int row = blockIdx.x * 4 + wid;  // b*TT + t
  const int b = row >> 10;
  const int t = row & (TT - 1);
  int L = lens[b];
  if (L < 1) L = 1;
  if (L > TT) L = TT;
  if (t >= L) return;
  float4 p = ((const float4*)pot)[(size_t)row * 64 + lane];
  const float m = wave_max64(fmaxf(fmaxf(p.x, p.y), fmaxf(p.z, p.w)));
  const int p1 = first_index_eq(p.x, p.y, p.z, p.w, m);
  unsigned long long m0, m1, m2, m3;
  int cnt, i2;
  band_scan(p.x, p.y, p.z, p.w, m - 0.21f, p1, m0, m1, m2, m3, cnt, i2);
  int lo = (p1 < i2) ? p1 : i2;
  int hi = (p1 < i2) ? i2 : p1;
  if (cnt < 2) { lo = p1; hi = p1; }
  if (cnt > 3) cnt = 3;
  if (lane == 0)
    recs[row] = (uint32_t)lo | ((uint32_t)hi << 8) | ((uint32_t)cnt << 16);
}

// ---------- forward state + step functions (templated on load style) ----------
struct VState {
  float a0, a1, a2, a3;
  f32x4 loTr, hiTr;
  float loA, hiA;
  int loI, hiI, istar;
  bool cnt1, big;
  unsigned long long m0, m1, m2, m3;
};

template <bool ASM>
__device__ __forceinline__ f32x4 row_load(const float* __restrict__ trans,
                                          int row, int voff16, int l) {
  f32x4 r;
  if constexpr (ASM) {
    const ull a_ = (ull)trans + ((ull)row << 10);
    asm volatile("global_load_dwordx4 %0, %1, %2"
                 : "=v"(r) : "v"(voff16), "s"(a_));
    asm volatile("s_waitcnt vmcnt(0)" ::: "memory");  // rare-path self-drain
    __builtin_amdgcn_sched_barrier(0);
  } else {
    r = ((const f32x4*)(trans + (size_t)row * NN))[l];
  }
  return r;
}

template <bool ASM>
__device__ __forceinline__ void classify_f(VState& st, uint32_t rec,
                                           const f32x4& rL, const f32x4& rH,
                                           const float* __restrict__ trans,
                                           int voff16, int l) {
  const int lo = (int)(rec & 255), hi = (int)((rec >> 8) & 255);
  const int pcnt = (int)((rec >> 16) & 255);
  if (pcnt <= 2) {
    st.big = false;
    const float aL = rl_pick(st.a0, st.a1, st.a2, st.a3, lo);
    const float aH = rl_pick(st.a0, st.a1, st.a2, st.a3, hi);
    const bool hw = (aH > aL);  // strict: tie -> smaller index lo
    const float M = hw ? aH : aL;
    st.istar = hw ? hi : lo;
    const bool two = (pcnt == 2) && (fminf(aL, aH) >= M - 0.105f);
    st.cnt1 = !two;
    st.loI = two ? lo : st.istar;
    st.hiI = two ? hi : st.istar;
    st.loA = two ? aL : M;
    st.hiA = two ? aH : M;
    const bool sH1 = (!two) && hw;  // loTr = sH1 ? rH : rL
    const bool sH2 = two || hw;     // hiTr = sH2 ? rH : rL
    st.loTr[0] = sH1 ? rH[0] : rL[0]; st.loTr[1] = sH1 ? rH[1] : rL[1];
    st.loTr[2] = sH1 ? rH[2] : rL[2]; st.loTr[3] = sH1 ? rH[3] : rL[3];
    st.hiTr[0] = sH2 ? rH[0] : rL[0]; st.hiTr[1] = sH2 ? rH[1] : rL[1];
    st.hiTr[2] = sH2 ? rH[2] : rL[2]; st.hiTr[3] = sH2 ? rH[3] : rL[3];
  } else {
    const float M =
        wave_max64(fmaxf(fmaxf(st.a0, st.a1), fmaxf(st.a2, st.a3)));
    st.istar = first_index_eq(st.a0, st.a1, st.a2, st.a3, M);
    int cnt, i2c;
    band_scan(st.a0, st.a1, st.a2, st.a3, M - 0.105f, st.istar, st.m0, st.m1,
              st.m2, st.m3, cnt, i2c);
    f32x4 rI, r2;
    if (st.istar == lo) rI = rL;
    else if (st.istar == hi) rI = rH;
    else rI = row_load<ASM>(trans, st.istar, voff16, l);
    if (i2c == lo) r2 = rL;
    else if (i2c == hi) r2 = rH;
    else if (i2c == st.istar) r2 = rI;
    else r2 = row_load<ASM>(trans, i2c, voff16, l);
    if (cnt == 1) {
      st.cnt1 = true; st.big = false;
      st.loI = st.istar; st.hiI = st.istar; st.loA = M; st.hiA = M;
      st.loTr = rI; st.hiTr = rI;
    } else if (cnt == 2) {
      st.cnt1 = false; st.big = false;
      if (st.istar < i2c) {
        st.loI = st.istar; st.loA = M; st.loTr = rI;
        st.hiI = i2c; st.hiA = rl_pick(st.a0, st.a1, st.a2, st.a3, i2c);
        st.hiTr = r2;
      } else {
        st.loI = i2c; st.loA = rl_pick(st.a0, st.a1, st.a2, st.a3, i2c);
        st.loTr = r2;
        st.hiI = st.istar; st.hiA = M; st.hiTr = rI;
      }
    } else {
      st.cnt1 = false; st.big = true;
      st.loI = st.istar; st.loA = M; st.loTr = rI;
      st.hiI = i2c; st.hiA = rl_pick(st.a0, st.a1, st.a2, st.a3, i2c);
      st.hiTr = r2;
    }
  }
}

template <bool ASM>
__device__ __forceinline__ void consume_f(VState& st, const f32x4& pT,
                                          uint32_t& bpword, uint32_t& rcByte,
                                          const float* __restrict__ trans,
                                          int voff16, int l) {
  float w0, w1, w2, w3;
  int j0, j1, j2, j3;
  if (!st.big) {
    float sl, sh;
    sl = st.loA + st.loTr[0]; sh = st.hiA + st.hiTr[0];
    w0 = (sh > sl) ? sh : sl; j0 = (sh > sl) ? st.hiI : st.loI;
    sl = st.loA + st.loTr[1]; sh = st.hiA + st.hiTr[1];
    w1 = (sh > sl) ? sh : sl; j1 = (sh > sl) ? st.hiI : st.loI;
    sl = st.loA + st.loTr[2]; sh = st.hiA + st.hiTr[2];
    w2 = (sh > sl) ? sh : sl; j2 = (sh > sl) ? st.hiI : st.loI;
    sl = st.loA + st.loTr[3]; sh = st.hiA + st.hiTr[3];
    w3 = (sh > sl) ? sh : sl; j3 = (sh > sl) ? st.hiI : st.loI;
  } else {
    w0 = w1 = w2 = w3 = -INFINITY;
    j0 = j1 = j2 = j3 = 0;
    unsigned long long comb = st.m0 | st.m1 | st.m2 | st.m3;
    while (comb) {
      const int q = __builtin_ctzll(comb);
      comb &= comb - 1;
      const unsigned qbits = (unsigned)(((st.m0 >> q) & 1ull) |
                                        (((st.m1 >> q) & 1ull) << 1) |
                                        (((st.m2 >> q) & 1ull) << 2) |
                                        (((st.m3 >> q) & 1ull) << 3));
      const float aq0 =
          __int_as_float(__builtin_amdgcn_readlane(__float_as_int(st.a0), q));
      const float aq1 =
          __int_as_float(__builtin_amdgcn_readlane(__float_as_int(st.a1), q));
      const float aq2 =
          __int_as_float(__builtin_amdgcn_readlane(__float_as_int(st.a2), q));
      const float aq3 =
          __int_as_float(__builtin_amdgcn_readlane(__float_as_int(st.a3), q));
#pragma unroll
      for (int g = 0; g < 4; ++g) {
        if ((qbits >> g) & 1) {
          const int i = 4 * q + g;
          const float ai =
              (g == 0) ? aq0 : (g == 1) ? aq1 : (g == 2) ? aq2 : aq3;
          f32x4 tr;
          if (i == st.loI) tr = st.loTr;
          else if (i == st.hiI) tr = st.hiTr;
          else tr = row_load<ASM>(trans, i, voff16, l);
          float sv;
          sv = ai + tr[0]; if (sv > w0) { w0 = sv; j0 = i; }
          sv = ai + tr[1]; if (sv > w1) { w1 = sv; j1 = i; }
          sv = ai + tr[2]; if (sv > w2) { w2 = sv; j2 = i; }
          sv = ai + tr[3]; if (sv > w3) { w3 = sv; j3 = i; }
        }
      }
    }
  }
  bpword = (uint32_t)j0 | ((uint32_t)j1 << 8) | ((uint32_t)j2 << 16) |
           ((uint32_t)j3 << 24);
  rcByte = st.cnt1 ? (uint32_t)st.loI : 255u;
  st.a0 = w0 + pT[0]; st.a1 = w1 + pT[1];
  st.a2 = w2 + pT[2]; st.a3 = w3 + pT[3];
}

// ---------- forward Viterbi: LDS-streamed, ROLLED chunk body ----------
// R5's verified memory machinery (LDS double-buffered 8-step chunks via
// global_load_lds, vmcnt(33)/lgkmcnt(3) counted waits) with the chunk body
// ROLLED (2-step ping-pong, unroll disabled): body ~10KB instead of ~30KB.
// Theory: R5 was I$-capacity-bound (~650cy/step fetch stall).
__global__ __launch_bounds__(64, 1) void fwd_kernel(
    const float* __restrict__ pot, const float* __restrict__ trans,
    const int* __restrict__ lens, const uint32_t* __restrict__ recs,
    uint8_t* __restrict__ bp, uint8_t* __restrict__ rowc,
    int* __restrict__ last_tag) {
  __shared__ __align__(16) float s_buf[2][8 * 768];  // 2 x 24KB stream
  __shared__ __align__(16) uint32_t s_rec[TT];       // 4KB rec mirror
  const int b = blockIdx.x;
  const int l = threadIdx.x;
  int L = lens[b];
  if (L < 1) L = 1;
  if (L > TT) L = TT;
  const int Lm1 = L - 1;
  const float* potb = pot + (size_t)b * TT * NN;
  const uint32_t* recb = recs + (size_t)b * TT;
  const ull bpB = (ull)bp + (ull)b * TT * NN;
  const ull rcB = (ull)rowc + (ull)b * TT;
  const int voff16 = l * 16;
  const int voff4 = l * 4;
  const int vzero = 0;

  // rec mirror -> LDS (C++: before any asm/staging; DS FIFO per-wave ordered)
  {
    const uint4* src = (const uint4*)recb;
    uint4* dst4 = (uint4*)s_rec;
#pragma unroll
    for (int i = 0; i < 4; ++i) dst4[l + 64 * i] = src[l + 64 * i];
  }
  const uint32_t recbase = (uint32_t)(ull)&s_rec[0];
  const uint32_t bufb0 = (uint32_t)(ull)&s_buf[0][0];
  const uint32_t bufb1 = (uint32_t)(ull)&s_buf[1][0];

  // async stage of one step's 3KB into LDS slot k of buffer bufsel
  auto stage_step = [&](int bufsel, int k, uint32_t rec, int t) {
    const int lo = (int)(rec & 255), hi = (int)((rec >> 8) & 255);
    int tp = t; if (tp > TT - 1) tp = TT - 1;
    const float* gL = trans + (size_t)lo * NN + (size_t)l * 4;
    const float* gH = trans + (size_t)hi * NN + (size_t)l * 4;
    const float* gP = potb + (size_t)tp * NN + (size_t)l * 4;
    float* dst = &s_buf[bufsel][k * 768];
    __builtin_amdgcn_global_load_lds(
        (const __attribute__((address_space(1))) void*)gL,
        (__attribute__((address_space(3))) void*)dst, 16, 0, 0);
    __builtin_amdgcn_global_load_lds(
        (const __attribute__((address_space(1))) void*)gH,
        (__attribute__((address_space(3))) void*)(dst + 256), 16, 0, 0);
    __builtin_amdgcn_global_load_lds(
        (const __attribute__((address_space(1))) void*)gP,
        (__attribute__((address_space(3))) void*)(dst + 512), 16, 0, 0);
  };

  // ---- state init + alpha_0 ----
  VState st;
  st.loI = 0; st.hiI = 0; st.istar = 0;
  st.loA = 0.f; st.hiA = 0.f;
  st.loTr = (f32x4)0.f; st.hiTr = (f32x4)0.f;
  st.cnt1 = true; st.big = false;
  st.m0 = 0; st.m1 = 0; st.m2 = 0; st.m3 = 0;
  {
    f32x4 p0 = ((const f32x4*)potb)[l];
    st.a0 = p0[0]; st.a1 = p0[1]; st.a2 = p0[2]; st.a3 = p0[3];
  }

  // ---- C++ prologue: rec0 + rows, classify step 0 ----
  const uint32_t rec0 = recb[0];
  {
    const int lo = (int)(rec0 & 255), hi = (int)((rec0 >> 8) & 255);
    const f32x4 c0L = ((const f32x4*)(trans + (size_t)lo * NN))[l];
    const f32x4 c0H = ((const f32x4*)(trans + (size_t)hi * NN))[l];
    classify_f<false>(st, rec0, c0L, c0H, trans, voff16, l);
  }

  // rec VGPR pipeline: rvCur = chunk0 recs (steps 1..8) in lanes (l&7),
  // rvNxt = chunk1 recs (steps 9..16). Per-lane C++ loads.
  int rvCur, rvNxt;
  {
    int u1 = 1 + (l & 7); if (u1 > Lm1) u1 = Lm1;
    int u2 = 9 + (l & 7); if (u2 > Lm1) u2 = Lm1;
    rvCur = (int)recb[u1];
    rvNxt = (int)recb[u2];
  }

  // scalar recs for prologue staging of chunks 0 and 1
  {
    uint32_t c0 = recb[1 <= Lm1 ? 1 : Lm1], c1 = recb[2 <= Lm1 ? 2 : Lm1];
    uint32_t c2 = recb[3 <= Lm1 ? 3 : Lm1], c3 = recb[4 <= Lm1 ? 4 : Lm1];
    uint32_t c4 = recb[5 <= Lm1 ? 5 : Lm1], c5 = recb[6 <= Lm1 ? 6 : Lm1];
    uint32_t c6 = recb[7 <= Lm1 ? 7 : Lm1], c7 = recb[8 <= Lm1 ? 8 : Lm1];
    uint32_t n0 = recb[9 <= Lm1 ? 9 : Lm1], n1 = recb[10 <= Lm1 ? 10 : Lm1];
    uint32_t n2 = recb[11 <= Lm1 ? 11 : Lm1], n3 = recb[12 <= Lm1 ? 12 : Lm1];
    uint32_t n4 = recb[13 <= Lm1 ? 13 : Lm1], n5 = recb[14 <= Lm1 ? 14 : Lm1];
    uint32_t n6 = recb[15 <= Lm1 ? 15 : Lm1], n7 = recb[16 <= Lm1 ? 16 : Lm1];
    stage_step(0, 0, c0, 1); stage_step(0, 1, c1, 2);
    stage_step(0, 2, c2, 3); stage_step(0, 3, c3, 4);
    stage_step(0, 4, c4, 5); stage_step(0, 5, c5, 6);
    stage_step(0, 6, c6, 7); stage_step(0, 7, c7, 8);
    stage_step(1, 0, n0, 9); stage_step(1, 1, n1, 10);
    stage_step(1, 2, n2, 11); stage_step(1, 3, n3, 12);
    stage_step(1, 4, n4, 13); stage_step(1, 5, n5, 14);
    stage_step(1, 6, n6, 15); stage_step(1, 7, n7, 16);
  }
  asm volatile("s_waitcnt vmcnt(24)" ::: "memory");  // chunk0 landed
  __builtin_amdgcn_sched_barrier(0);

#define DSR4(dst, byteoff)                                         \
  {                                                                \
    uint32_t va_ = (uint32_t)(byteoff) + (uint32_t)voff16;         \
    asm volatile("ds_read_b128 %0, %1" : "=v"(dst) : "v"(va_));    \
  }

  const int nfull = Lm1 >> 3;  // full 8-step chunks: steps 1..8*nfull
  for (int n = 0; n < nfull; ++n) {
    const int tb = 1 + n * 8;
    const uint32_t bb = (n & 1) ? bufb1 : bufb0;
    ull rcAll = 0;
    f32x4 AL, AH, AP, BL, BH, BP;
    DSR4(AL, bb + 0); DSR4(AH, bb + 1024); DSR4(AP, bb + 2048);

    // ---- rolled chunk body: 2-step ping-pong, DO NOT UNROLL ----
#pragma clang loop unroll(disable)
    for (int kk = 0; kk < 8; kk += 2) {
      const int t0 = tb + kk;
      // even step kk: consume A (slot kk), prefetch slot kk+1 into B
      {
        const uint32_t off1 = bb + (uint32_t)(kk + 1) * 3072;
        DSR4(BL, off1 + 0); DSR4(BH, off1 + 1024); DSR4(BP, off1 + 2048);
        asm volatile("s_waitcnt lgkmcnt(3)" ::: "memory");
        __builtin_amdgcn_sched_barrier(0);
        uint32_t bpw_, rc_;
        consume_f<true>(st, AP, bpw_, rc_, trans, voff16, l);
        asm volatile("global_store_dword %0, %1, %2" ::"v"(voff4),
                     "v"(bpw_), "s"(bpB + (ull)t0 * 256));
        rcAll |= ((ull)rc_) << (8 * kk);
        const uint32_t recE =
            (uint32_t)__builtin_amdgcn_readlane(rvCur, kk);
        classify_f<true>(st, recE, AL, AH, trans, voff16, l);
      }
      // odd step kk+1: consume B (slot kk+1), prefetch slot kk+2 into A
      {
        if (kk < 6) {
          const uint32_t off2 = bb + (uint32_t)(kk + 2) * 3072;
          DSR4(AL, off2 + 0); DSR4(AH, off2 + 1024); DSR4(AP, off2 + 2048);
          asm volatile("s_waitcnt lgkmcnt(3)" ::: "memory");
        } else {
          asm volatile("s_waitcnt lgkmcnt(0)" ::: "memory");
        }
        __builtin_amdgcn_sched_barrier(0);
        uint32_t bpw_, rc_;
        consume_f<true>(st, BP, bpw_, rc_, trans, voff16, l);
        asm volatile("global_store_dword %0, %1, %2" ::"v"(voff4),
                     "v"(bpw_), "s"(bpB + (ull)(t0 + 1) * 256));
        rcAll |= ((ull)rc_) << (8 * (kk + 1));
        const uint32_t recO =
            (uint32_t)__builtin_amdgcn_readlane(rvCur, kk + 1);
        classify_f<true>(st, recO, BL, BH, trans, voff16, l);
      }
    }

    // rowc bytes for t=tb..tb+7 (wave-uniform value; all lanes, same addr)
    asm volatile("global_store_dwordx2 %0, %1, %2" ::"v"(vzero),
                 "v"(rcAll), "s"(rcB + (ull)(tb - 1)));

    // ---- boundary: read chunk n+2 recs, stage chunk n+2, rotate rv ----
    {
      const int cs = 1 + 8 * (n + 2);
      int u = cs + (l & 7);
      if (u > Lm1) u = Lm1;
      const uint32_t va = recbase + ((uint32_t)u << 2);
      int rvNew;
      asm volatile("ds_read_b32 %0, %1" : "=v"(rvNew) : "v"(va));
      asm volatile("s_waitcnt lgkmcnt(0)" ::: "memory");
      __builtin_amdgcn_sched_barrier(0);
      const uint32_t s0 = (uint32_t)__builtin_amdgcn_readlane(rvNew, 0);
      const uint32_t s1 = (uint32_t)__builtin_amdgcn_readlane(rvNew, 1);
      const uint32_t s2 = (uint32_t)__builtin_amdgcn_readlane(rvNew, 2);
      const uint32_t s3 = (uint32_t)__builtin_amdgcn_readlane(rvNew, 3);
      const uint32_t s4 = (uint32_t)__builtin_amdgcn_readlane(rvNew, 4);
      const uint32_t s5 = (uint32_t)__builtin_amdgcn_readlane(rvNew, 5);
      const uint32_t s6 = (uint32_t)__builtin_amdgcn_readlane(rvNew, 6);
      const uint32_t s7 = (uint32_t)__builtin_amdgcn_readlane(rvNew, 7);
      stage_step(n & 1, 0, s0, cs + 0); stage_step(n & 1, 1, s1, cs + 1);
      stage_step(n & 1, 2, s2, cs + 2); stage_step(n & 1, 3, s3, cs + 3);
      stage_step(n & 1, 4, s4, cs + 4); stage_step(n & 1, 5, s5, cs + 5);
      stage_step(n & 1, 6, s6, cs + 6); stage_step(n & 1, 7, s7, cs + 7);
      rvCur = rvNxt;
      rvNxt = rvNew;
    }
    // 24 staging(n+2) + 9 stores(this chunk) newest -> stage(n+1) complete
    asm volatile("s_waitcnt vmcnt(33)" ::: "memory");
    __builtin_amdgcn_sched_barrier(0);
  }
#undef DSR4

  // ---- full drain, then C++ demand tail (<= 7 steps) ----
  asm volatile("s_waitcnt vmcnt(0) lgkmcnt(0)" ::: "memory");
  __builtin_amdgcn_sched_barrier(0);
  for (int t = 1 + 8 * nfull; t < L; ++t) {
    const f32x4 pT = ((const f32x4*)(potb + (size_t)t * NN))[l];
    uint32_t bpw_, rc_;
    consume_f<false>(st, pT, bpw_, rc_, trans, voff16, l);
    ((uint32_t*)(bp + (size_t)b * TT * NN))[(size_t)t * 64 + l] = bpw_;
    if (l == 0) rowc[(size_t)b * TT + t - 1] = (uint8_t)rc_;
    const uint32_t srT =
        (uint32_t)__builtin_amdgcn_readfirstlane((int)recb[t]);
    const int lo = (int)(srT & 255), hi = (int)((srT >> 8) & 255);
    const f32x4 rL = ((const f32x4*)(trans + (size_t)lo * NN))[l];
    const f32x4 rH = ((const f32x4*)(trans + (size_t)hi * NN))[l];
    classify_f<false>(st, srT, rL, rH, trans, voff16, l);
  }

  if (l == 0) last_tag[b] = st.istar;
}

// ---------- backtrace phase 1: chase start tags through each 64-chunk ----------
// rowc layout: byte index (t-1) holds the marker for step t.
__global__ __launch_bounds__(256) void chase_kernel(
    const uint8_t* __restrict__ bp, const uint8_t* __restrict__ rowc,
    const int* __restrict__ lens, uint8_t* __restrict__ traj) {
  const int bc = blockIdx.x;  // b*16 + c
  const int b = bc >> 4, c = bc & 15;
  const int j = threadIdx.x;
  int L = lens[b];
  if (L < 1) L = 1;
  if (L > TT) L = TT;
  const uint8_t* bpb = bp + (size_t)b * TT * NN;
  uint8_t* trj = traj + (size_t)bc * 64 * NN;
  uint32_t rcw[16];
  {
    const uint4* src = (const uint4*)(rowc + (size_t)b * TT + (c << 6));
    uint4 x0 = src[0], x1 = src[1], x2 = src[2], x3 = src[3];
    rcw[0] = x0.x; rcw[1] = x0.y; rcw[2] = x0.z; rcw[3] = x0.w;
    rcw[4] = x1.x; rcw[5] = x1.y; rcw[6] = x1.z; rcw[7] = x1.w;
    rcw[8] = x2.x; rcw[9] = x2.y; rcw[10] = x2.z; rcw[11] = x2.w;
    rcw[12] = x3.x; rcw[13] = x3.y; rcw[14] = x3.z; rcw[15] = x3.w;
  }
  int tag = j;
  trj[63 * NN + j] = (uint8_t)tag;
#pragma unroll
  for (int k = 62; k >= 0; --k) {
    const int t = (c << 6) + k + 1;
    if (t < L) {  // L uniform per block -> uniform branches
      const int rc = (rcw[k >> 2] >> ((k & 3) * 8)) & 255;  // byte t-1
      if (rc != 255) tag = rc;            // constant bp row: no gather
      else tag = bpb[t * NN + tag];       // multi row: gather
    }
    trj[k * NN + j] = (uint8_t)tag;
  }
}

// ---------- backtrace phase 2: serial compose across 16 chunks/batch ----------
__global__ void compose_kernel(const uint8_t* __restrict__ bp,
                               const uint8_t* __restrict__ rowc,
                               const uint8_t* __restrict__ traj,
                               const int* __restrict__ last_tag,
                               const int* __restrict__ lens,
                               int* __restrict__ enter) {
  const int b = threadIdx.x;
  if (b >= BB) return;
  int L = lens[b];
  if (L < 1) L = 1;
  if (L > TT) L = TT;
  int e = last_tag[b];
  enter[b * 16 + 15] = e;
  for (int c = 15; c >= 1; --c) {
    int bottom = traj[((size_t)(b * 16 + c) * 64 + 0) * NN + e];
    const int t = c << 6;
    int nx = bottom;
    if (t < L) {
      const int rc = rowc[(size_t)b * TT + t - 1];  // byte t-1
      if (rc != 255) nx = rc;
      else nx = bp[(size_t)b * TT * NN + (size_t)t * NN + bottom];
    }
    e = nx;
    enter[b * 16 + c - 1] = e;
  }
}

// ---------- backtrace phase 3: emit tags (0 for t >= L) ----------
__global__ __launch_bounds__(256) void tags_kernel(
    const uint8_t* __restrict__ traj, const int* __restrict__ enter,
    const int* __restrict__ lens, uint8_t* __restrict__ tags) {
  const int idx = blockIdx.x * 256 + threadIdx.x;  // 0..B*T-1
  const int b = idx >> 10, t = idx & (TT - 1);
  int L = lens[b];
  if (L < 1) L = 1;
  if (L > TT) L = TT;
  int tag = 0;
  if (t < L) {
    const int c = t >> 6, k = t & 63;
    const int e = enter[b * 16 + c];
    tag = traj[((size_t)(b * 16 + c) * 64 + k) * NN + e];
  }
  tags[idx] = (uint8_t)tag;
}

// ---------- one-hot writer: wave per (b,t) row, float4 stores ----------
__global__ __launch_bounds__(256) void onehot_kernel(
    const uint8_t* __restrict__ tags, float* __restrict__ out) {
  const int wid = threadIdx.x >> 6, lane = threadIdx.x & 63;
  const int r = blockIdx.x * 4 + wid;  // row over B*T
  const int tag = tags[r];
  const int n0 = lane * 4;
  float4 v;
  v.x = (n0 == tag) ? 1.f : 0.f;
  v.y = (n0 + 1 == tag) ? 1.f : 0.f;
  v.z = (n0 + 2 == tag) ? 1.f : 0.f;
  v.w = (n0 + 3 == tag) ? 1.f : 0.f;
  ((float4*)out)[(size_t)r * 64 + lane] = v;
}

extern "C" void kernel_launch(void* const* d_in, const int* in_sizes, int n_in,
                              void* d_out, int out_size, void* d_ws,
                              size_t ws_size, hipStream_t stream) {
  const float* pot = (const float*)d_in[0];
  const float* trans = (const float*)d_in[1];
  const int* lens = (const int*)d_in[2];
  float* out = (float*)d_out;

  // Scratch inside d_out (128 MiB): all consumed before onehot overwrites it;
  // onehot reads only tags (in d_ws).
  uint8_t* base = (uint8_t*)d_out;
  uint8_t* bp = base;                                        // 33,554,432 B
  uint8_t* traj = base + (size_t)BB * TT * NN;               // 33,554,432 B
  uint8_t* rowc = base + (size_t)2 * BB * TT * NN;           // 131,072 B
  int* last_tag = (int*)(base + (size_t)2 * BB * TT * NN + BB * TT);  // 512 B
  int* enter = (int*)(base + (size_t)2 * BB * TT * NN + BB * TT + 512);
  uint32_t* recs = (uint32_t*)(base + (size_t)65 * 1024 * 1024);  // 524,288 B
  uint8_t* tags = (uint8_t*)d_ws;                            // 131,072 B

  prep_kernel<<<BB * TT / 4, 256, 0, stream>>>(pot, lens, recs);
  fwd_kernel<<<BB, 64, 0, stream>>>(pot, trans, lens, recs, bp, rowc, last_tag);
  chase_kernel<<<BB * 16, 256, 0, stream>>>(bp, rowc, lens, traj);
  compose_kernel<<<1, 128, 0, stream>>>(bp, rowc, traj, last_tag, lens, enter);
  tags_kernel<<<BB * TT / 256, 256, 0, stream>>>(traj, enter, lens, tags);
  onehot_kernel<<<BB * TT / 4, 256, 0, stream>>>(tags, out);
}